// Round 4
// baseline (3959.103 us; speedup 1.0000x reference)
//
#include <hip/hip_runtime.h>
#include <cstdint>

#define NPOS 32768
#define IND  512
#define HID  512
#define OUTF 256

// ---------------------------------------------------------------------------
// K0: transpose W2 [256][512] -> w2t [512][256] (pure copy; values exact)
// ---------------------------------------------------------------------------
__global__ __launch_bounds__(256) void k_transpose(const float* __restrict__ W2,
                                                   float* __restrict__ w2t) {
  __shared__ float tile[32][33];
  int x = threadIdx.x & 31, y = threadIdx.x >> 5;  // 32 x 8
  int hb = blockIdx.x * 32, ob = blockIdx.y * 32;
#pragma unroll
  for (int dy = 0; dy < 32; dy += 8)
    tile[y + dy][x] = W2[(size_t)(ob + y + dy) * HID + hb + x];
  __syncthreads();
#pragma unroll
  for (int dy = 0; dy < 32; dy += 8)
    w2t[(size_t)(hb + y + dy) * OUTF + ob + x] = tile[x][y + dy];
}

// ---------------------------------------------------------------------------
// K1: fc1 GEMM, fp32, BIT-EXACT strict-sequential model of the np reference:
// pre1[pos,h] = fold over i=0..511 ascending of acc = fadd(acc, fmul(x,w)),
// single accumulator, separate mul+add (NO FMA), then pre = fadd(acc, b1[h]).
// Fused LIF-period epilogue: kmap[pos][h] = first t (1..16) where the exact
// fp32 cumulative sum of pre exceeds 0.5 (0 = never). Spike train is exactly
// periodic with that k (reset is exact 0.0, so the fp32 sequence repeats).
// 128x128 tile, 8x8 microtile, 256 threads.
// ---------------------------------------------------------------------------
__global__ __launch_bounds__(256) void k_fc1_kmap(const float* __restrict__ X,
                                                  const float* __restrict__ W1,
                                                  const float* __restrict__ b1,
                                                  unsigned char* __restrict__ kmap) {
  __shared__ float As[8][128];
  __shared__ float Bs[8][128];
  const int row0 = blockIdx.x * 128;   // position tile (32768/128 = 256)
  const int col0 = blockIdx.y * 128;   // hidden tile   (512/128 = 4)
  const int t = threadIdx.x;
  const int tm0 = (t & 15) * 8;
  const int tn0 = (t >> 4) * 8;

  float c[8][8];
#pragma unroll
  for (int i = 0; i < 8; ++i)
#pragma unroll
    for (int j = 0; j < 8; ++j) c[i][j] = 0.0f;

  const int sm = t >> 1;          // 0..127
  const int sk = (t & 1) * 4;     // 0 or 4

  for (int kt = 0; kt < IND; kt += 8) {
    float4 va = *(const float4*)(X + (size_t)(row0 + sm) * IND + kt + sk);
    float4 vb = *(const float4*)(W1 + (size_t)(col0 + sm) * IND + kt + sk);
    __syncthreads();   // protect previous iteration's LDS reads
    As[sk + 0][sm] = va.x; As[sk + 1][sm] = va.y;
    As[sk + 2][sm] = va.z; As[sk + 3][sm] = va.w;
    Bs[sk + 0][sm] = vb.x; Bs[sk + 1][sm] = vb.y;
    Bs[sk + 2][sm] = vb.z; Bs[sk + 3][sm] = vb.w;
    __syncthreads();
#pragma unroll
    for (int kk = 0; kk < 8; ++kk) {   // global i = kt + kk, strictly ascending
      float4 a0 = *(const float4*)&As[kk][tm0];
      float4 a1 = *(const float4*)&As[kk][tm0 + 4];
      float4 b0 = *(const float4*)&Bs[kk][tn0];
      float4 b1_ = *(const float4*)&Bs[kk][tn0 + 4];
      float a[8] = {a0.x, a0.y, a0.z, a0.w, a1.x, a1.y, a1.z, a1.w};
      float b[8] = {b0.x, b0.y, b0.z, b0.w, b1_.x, b1_.y, b1_.z, b1_.w};
#pragma unroll
      for (int i = 0; i < 8; ++i)
#pragma unroll
        for (int j = 0; j < 8; ++j)
          c[i][j] = __fadd_rn(c[i][j], __fmul_rn(a[i], b[j]));  // no contraction
    }
  }

  // epilogue: pre1 = dot + b1; exact fp32 16-step crossing search
  float4 b1a = *(const float4*)(b1 + col0 + tn0);
  float4 b1b = *(const float4*)(b1 + col0 + tn0 + 4);
  float b1v[8] = {b1a.x, b1a.y, b1a.z, b1a.w, b1b.x, b1b.y, b1b.z, b1b.w};

#pragma unroll
  for (int i = 0; i < 8; ++i) {
    unsigned long long pk = 0;
#pragma unroll
    for (int j = 0; j < 8; ++j) {
      float pre = __fadd_rn(c[i][j], b1v[j]);
      float m = 0.0f;
      int kv = 0;
#pragma unroll
      for (int tt = 1; tt <= 16; ++tt) {
        m = __fadd_rn(m, pre);
        if (m > 0.5f && kv == 0) kv = tt;
      }
      pk |= (unsigned long long)(unsigned int)kv << (8 * j);
    }
    *(unsigned long long*)(kmap + (size_t)(row0 + tm0 + i) * HID + col0 + tn0) = pk;
  }
}

// ---------------------------------------------------------------------------
// K2: exact-order fc2 + mem2 simulation. For each (pos, o):
// c_t[o] = sum over h ASCENDING of W2[o,h] where (k_h | t) — a strict
// sequential fp32 chain per t (skipping non-spiking h adds exact +0.0, a
// bitwise no-op). Implemented as acc[16] registers updated via a
// wave-uniform switch on k_h (static indices only). Then
// mem2 = (mem2 + c_t) + b2, spike > 0.5, reset — all exact fp32.
// Block = 256 threads = one position; thread owns o = tid.
// ---------------------------------------------------------------------------
__device__ __forceinline__ void bump(float (&acc)[16], int k, float w) {
  switch (k) {
    case 1:
      acc[0] += w;  acc[1] += w;  acc[2] += w;  acc[3] += w;
      acc[4] += w;  acc[5] += w;  acc[6] += w;  acc[7] += w;
      acc[8] += w;  acc[9] += w;  acc[10] += w; acc[11] += w;
      acc[12] += w; acc[13] += w; acc[14] += w; acc[15] += w;
      break;
    case 2:
      acc[1] += w;  acc[3] += w;  acc[5] += w;  acc[7] += w;
      acc[9] += w;  acc[11] += w; acc[13] += w; acc[15] += w;
      break;
    case 3:
      acc[2] += w; acc[5] += w; acc[8] += w; acc[11] += w; acc[14] += w;
      break;
    case 4:
      acc[3] += w; acc[7] += w; acc[11] += w; acc[15] += w;
      break;
    case 5:  acc[4] += w; acc[9] += w; acc[14] += w; break;
    case 6:  acc[5] += w; acc[11] += w; break;
    case 7:  acc[6] += w; acc[13] += w; break;
    case 8:  acc[7] += w; acc[15] += w; break;
    case 9:  acc[8] += w; break;
    case 10: acc[9] += w; break;
    case 11: acc[10] += w; break;
    case 12: acc[11] += w; break;
    case 13: acc[12] += w; break;
    case 14: acc[13] += w; break;
    case 15: acc[14] += w; break;
    default: acc[15] += w; break;  // k == 16
  }
}

__global__ __launch_bounds__(256) void k_snn_fc2(const unsigned char* __restrict__ kmap,
                                                 const float* __restrict__ w2t,
                                                 const float* __restrict__ b2,
                                                 float* __restrict__ out) {
  const int tid = threadIdx.x;            // o = tid
  const size_t pos = blockIdx.x;

  float acc[16];
#pragma unroll
  for (int i = 0; i < 16; ++i) acc[i] = 0.0f;

  const uint4* kp = (const uint4*)(kmap + pos * HID);

  for (int it = 0; it < 32; ++it) {       // h ascending in groups of 16
    uint4 kw = kp[it];                    // wave-uniform address
    unsigned wd[4] = {kw.x, kw.y, kw.z, kw.w};
#pragma unroll
    for (int d = 0; d < 4; ++d) {
      unsigned word = wd[d];
      int hbase = it * 16 + d * 4;
      int k0 = __builtin_amdgcn_readfirstlane((int)(word & 255u));
      if (k0) { float w = w2t[(size_t)(hbase + 0) * OUTF + tid]; bump(acc, k0, w); }
      int k1 = __builtin_amdgcn_readfirstlane((int)((word >> 8) & 255u));
      if (k1) { float w = w2t[(size_t)(hbase + 1) * OUTF + tid]; bump(acc, k1, w); }
      int k2 = __builtin_amdgcn_readfirstlane((int)((word >> 16) & 255u));
      if (k2) { float w = w2t[(size_t)(hbase + 2) * OUTF + tid]; bump(acc, k2, w); }
      int k3 = __builtin_amdgcn_readfirstlane((int)((word >> 24) & 255u));
      if (k3) { float w = w2t[(size_t)(hbase + 3) * OUTF + tid]; bump(acc, k3, w); }
    }
  }

  // mem2 simulation, exact fp32: mem = (mem + c_t) + b2; spike; reset.
  float b2v = b2[tid];
  float mem = 0.0f, ss = 0.0f;
#pragma unroll
  for (int tt = 0; tt < 16; ++tt) {
    mem = __fadd_rn(__fadd_rn(mem, acc[tt]), b2v);
    if (mem > 0.5f) { ss += 1.0f; mem = 0.0f; }
  }
  out[pos * OUTF + tid] = ss * 0.0625f;
}

// ---------------------------------------------------------------------------
extern "C" void kernel_launch(void* const* d_in, const int* in_sizes, int n_in,
                              void* d_out, int out_size, void* d_ws, size_t ws_size,
                              hipStream_t stream) {
  const float* X  = (const float*)d_in[0];   // [16,2048,512]
  const float* W1 = (const float*)d_in[1];   // [512,512]
  const float* b1 = (const float*)d_in[2];   // [512]
  const float* W2 = (const float*)d_in[3];   // [256,512]
  const float* b2 = (const float*)d_in[4];   // [256]
  float* out = (float*)d_out;                // [32768,256]

  float* w2t = (float*)d_ws;                                           // 512 KB
  unsigned char* kmap = (unsigned char*)d_ws + (size_t)HID * OUTF * 4; // 16 MB

  k_transpose<<<dim3(16, 8), 256, 0, stream>>>(W2, w2t);
  k_fc1_kmap<<<dim3(256, 4), 256, 0, stream>>>(X, W1, b1, kmap);
  k_snn_fc2<<<NPOS, 256, 0, stream>>>(kmap, w2t, b2, out);
}

// Round 5
// 1630.658 us; speedup vs baseline: 2.4279x; 2.4279x over previous
//
#include <hip/hip_runtime.h>
#include <cstdint>

#define NPOS 32768
#define IND  512
#define HID  512
#define OUTF 256

// ---------------------------------------------------------------------------
// K0: transpose W2 [256][512] -> w2t [512][256] (pure copy; values exact)
// ---------------------------------------------------------------------------
__global__ __launch_bounds__(256) void k_transpose(const float* __restrict__ W2,
                                                   float* __restrict__ w2t) {
  __shared__ float tile[32][33];
  int x = threadIdx.x & 31, y = threadIdx.x >> 5;  // 32 x 8
  int hb = blockIdx.x * 32, ob = blockIdx.y * 32;
#pragma unroll
  for (int dy = 0; dy < 32; dy += 8)
    tile[y + dy][x] = W2[(size_t)(ob + y + dy) * HID + hb + x];
  __syncthreads();
#pragma unroll
  for (int dy = 0; dy < 32; dy += 8)
    w2t[(size_t)(hb + y + dy) * OUTF + ob + x] = tile[x][y + dy];
}

// ---------------------------------------------------------------------------
// K1: fc1 GEMM, fp32, BIT-EXACT strict-sequential model of the np reference
// (single accumulator, ascending i, separate mul+add, no FMA), fused
// LIF-period epilogue -> kmap[pos][h] = first crossing step k (0 = never).
// UNCHANGED from the passing round-4 kernel.
// ---------------------------------------------------------------------------
__global__ __launch_bounds__(256) void k_fc1_kmap(const float* __restrict__ X,
                                                  const float* __restrict__ W1,
                                                  const float* __restrict__ b1,
                                                  unsigned char* __restrict__ kmap) {
  __shared__ float As[8][128];
  __shared__ float Bs[8][128];
  const int row0 = blockIdx.x * 128;   // position tile (32768/128 = 256)
  const int col0 = blockIdx.y * 128;   // hidden tile   (512/128 = 4)
  const int t = threadIdx.x;
  const int tm0 = (t & 15) * 8;
  const int tn0 = (t >> 4) * 8;

  float c[8][8];
#pragma unroll
  for (int i = 0; i < 8; ++i)
#pragma unroll
    for (int j = 0; j < 8; ++j) c[i][j] = 0.0f;

  const int sm = t >> 1;          // 0..127
  const int sk = (t & 1) * 4;     // 0 or 4

  for (int kt = 0; kt < IND; kt += 8) {
    float4 va = *(const float4*)(X + (size_t)(row0 + sm) * IND + kt + sk);
    float4 vb = *(const float4*)(W1 + (size_t)(col0 + sm) * IND + kt + sk);
    __syncthreads();   // protect previous iteration's LDS reads
    As[sk + 0][sm] = va.x; As[sk + 1][sm] = va.y;
    As[sk + 2][sm] = va.z; As[sk + 3][sm] = va.w;
    Bs[sk + 0][sm] = vb.x; Bs[sk + 1][sm] = vb.y;
    Bs[sk + 2][sm] = vb.z; Bs[sk + 3][sm] = vb.w;
    __syncthreads();
#pragma unroll
    for (int kk = 0; kk < 8; ++kk) {   // global i = kt + kk, strictly ascending
      float4 a0 = *(const float4*)&As[kk][tm0];
      float4 a1 = *(const float4*)&As[kk][tm0 + 4];
      float4 b0 = *(const float4*)&Bs[kk][tn0];
      float4 b1_ = *(const float4*)&Bs[kk][tn0 + 4];
      float a[8] = {a0.x, a0.y, a0.z, a0.w, a1.x, a1.y, a1.z, a1.w};
      float b[8] = {b0.x, b0.y, b0.z, b0.w, b1_.x, b1_.y, b1_.z, b1_.w};
#pragma unroll
      for (int i = 0; i < 8; ++i)
#pragma unroll
        for (int j = 0; j < 8; ++j)
          c[i][j] = __fadd_rn(c[i][j], __fmul_rn(a[i], b[j]));  // no contraction
    }
  }

  float4 b1a = *(const float4*)(b1 + col0 + tn0);
  float4 b1b = *(const float4*)(b1 + col0 + tn0 + 4);
  float b1v[8] = {b1a.x, b1a.y, b1a.z, b1a.w, b1b.x, b1b.y, b1b.z, b1b.w};

#pragma unroll
  for (int i = 0; i < 8; ++i) {
    unsigned long long pk = 0;
#pragma unroll
    for (int j = 0; j < 8; ++j) {
      float pre = __fadd_rn(c[i][j], b1v[j]);
      float m = 0.0f;
      int kv = 0;
#pragma unroll
      for (int tt = 1; tt <= 16; ++tt) {
        m = __fadd_rn(m, pre);
        if (m > 0.5f && kv == 0) kv = tt;
      }
      pk |= (unsigned long long)(unsigned int)kv << (8 * j);
    }
    *(unsigned long long*)(kmap + (size_t)(row0 + tm0 + i) * HID + col0 + tn0) = pk;
  }
}

// ---------------------------------------------------------------------------
// K2: exact-order fc2 + mem2 simulation — NAMED SCALAR accumulators.
// Same arithmetic as the passing round-4 kernel (c_t accumulated over h
// ascending, strict fp32), but a1..a16 are named scalars updated by an
// inlined wave-uniform switch -> guaranteed VGPR allocation (the acc[16]
// array version spilled: VGPR_Count=16, 8 GB scratch writes).
// Block = 256 threads = one position; thread owns o = tid.
// ---------------------------------------------------------------------------
__global__ __launch_bounds__(256) void k_snn_fc2(const unsigned char* __restrict__ kmap,
                                                 const float* __restrict__ w2t,
                                                 const float* __restrict__ b2,
                                                 float* __restrict__ out) {
  const int tid = threadIdx.x;            // o = tid
  const size_t pos = blockIdx.x;

  float a1 = 0.f, a2 = 0.f, a3 = 0.f, a4 = 0.f, a5 = 0.f, a6 = 0.f,
        a7 = 0.f, a8 = 0.f, a9 = 0.f, a10 = 0.f, a11 = 0.f, a12 = 0.f,
        a13 = 0.f, a14 = 0.f, a15 = 0.f, a16 = 0.f;

  const uint4* kp = (const uint4*)(kmap + pos * HID);

  for (int it = 0; it < 32; ++it) {       // h ascending in groups of 16
    uint4 kw = kp[it];                    // wave-uniform address
    unsigned wd[4] = {kw.x, kw.y, kw.z, kw.w};
#pragma unroll
    for (int d = 0; d < 4; ++d) {
      unsigned word = wd[d];
      int hbase = it * 16 + d * 4;
#pragma unroll
      for (int bb = 0; bb < 4; ++bb) {
        int k = __builtin_amdgcn_readfirstlane((int)((word >> (8 * bb)) & 255u));
        if (k) {
          float w = w2t[(size_t)(hbase + bb) * OUTF + tid];
          switch (k) {
            case 1:
              a1 += w;  a2 += w;  a3 += w;  a4 += w;
              a5 += w;  a6 += w;  a7 += w;  a8 += w;
              a9 += w;  a10 += w; a11 += w; a12 += w;
              a13 += w; a14 += w; a15 += w; a16 += w;
              break;
            case 2:
              a2 += w;  a4 += w;  a6 += w;  a8 += w;
              a10 += w; a12 += w; a14 += w; a16 += w;
              break;
            case 3:
              a3 += w; a6 += w; a9 += w; a12 += w; a15 += w;
              break;
            case 4:
              a4 += w; a8 += w; a12 += w; a16 += w;
              break;
            case 5:  a5 += w; a10 += w; a15 += w; break;
            case 6:  a6 += w; a12 += w; break;
            case 7:  a7 += w; a14 += w; break;
            case 8:  a8 += w; a16 += w; break;
            case 9:  a9 += w; break;
            case 10: a10 += w; break;
            case 11: a11 += w; break;
            case 12: a12 += w; break;
            case 13: a13 += w; break;
            case 14: a14 += w; break;
            case 15: a15 += w; break;
            default: a16 += w; break;  // k == 16
          }
        }
      }
    }
  }

  // mem2 simulation, exact fp32: mem = (mem + c_t) + b2; spike; reset.
  float b2v = b2[tid];
  float mem = 0.0f, ss = 0.0f;
#define STEP(CT)                                            \
  do {                                                      \
    mem = __fadd_rn(__fadd_rn(mem, (CT)), b2v);             \
    if (mem > 0.5f) { ss += 1.0f; mem = 0.0f; }             \
  } while (0)
  STEP(a1);  STEP(a2);  STEP(a3);  STEP(a4);
  STEP(a5);  STEP(a6);  STEP(a7);  STEP(a8);
  STEP(a9);  STEP(a10); STEP(a11); STEP(a12);
  STEP(a13); STEP(a14); STEP(a15); STEP(a16);
#undef STEP
  out[pos * OUTF + tid] = ss * 0.0625f;
}

// ---------------------------------------------------------------------------
extern "C" void kernel_launch(void* const* d_in, const int* in_sizes, int n_in,
                              void* d_out, int out_size, void* d_ws, size_t ws_size,
                              hipStream_t stream) {
  const float* X  = (const float*)d_in[0];   // [16,2048,512]
  const float* W1 = (const float*)d_in[1];   // [512,512]
  const float* b1 = (const float*)d_in[2];   // [512]
  const float* W2 = (const float*)d_in[3];   // [256,512]
  const float* b2 = (const float*)d_in[4];   // [256]
  float* out = (float*)d_out;                // [32768,256]

  float* w2t = (float*)d_ws;                                           // 512 KB
  unsigned char* kmap = (unsigned char*)d_ws + (size_t)HID * OUTF * 4; // 16 MB

  k_transpose<<<dim3(16, 8), 256, 0, stream>>>(W2, w2t);
  k_fc1_kmap<<<dim3(256, 4), 256, 0, stream>>>(X, W1, b1, kmap);
  k_snn_fc2<<<NPOS, 256, 0, stream>>>(kmap, w2t, b2, out);
}